// Round 1
// 491.973 us; speedup vs baseline: 1.7409x; 1.7409x over previous
//
#include <hip/hip_runtime.h>

// ---------------------------------------------------------------------------
// FeaturePropagationLayer (PointNet++ FP): 3-NN interp -> concat -> MLP(384->256)
// -> GN(32)+ReLU -> MLP(256->128) -> GN(32)+ReLU.  Output (B,N,128).
//
// Round 2: bf16 MFMA GEMMs (m97 recipe: 128x128 tile, BK=64, global_load_lds
// width 16, XOR-swizzled LDS, 16x16x32 bf16 MFMA).  Whole intermediate
// pipeline in bf16 (feat/h0/h0n/h1) to halve HBM traffic.  Weights converted
// once to bf16 in workspace (device-side dtype flag, no host branch).
// ---------------------------------------------------------------------------

#define DEVI __device__ __forceinline__

static constexpr int B  = 8;
static constexpr int N  = 8192;
static constexpr int M  = 2048;
static constexpr int C1 = 128;
static constexpr int C2 = 256;
static constexpr int CIN = C1 + C2;   // 384
static constexpr int H0 = 256;
static constexpr int H1 = 128;
static constexpr int BN = B * N;      // 65536

typedef __bf16 bf16x8 __attribute__((ext_vector_type(8)));
typedef float  f32x4  __attribute__((ext_vector_type(4)));
typedef unsigned short ushort8v __attribute__((ext_vector_type(8)));

DEVI float bf2f(unsigned short u) {
    union { unsigned int i; float f; } v; v.i = ((unsigned int)u) << 16; return v.f;
}
DEVI unsigned short f2bf(float f) {
    union { float f; unsigned int i; } v; v.f = f;
    unsigned int x = v.i;
    return (unsigned short)((x + 0x7fffu + ((x >> 16) & 1u)) >> 16);
}
// Flagged scalar input load: bf==1 -> bf16, else fp32.
DEVI float ldin(const void* p, size_t i, int bf) {
    return bf ? bf2f(((const unsigned short*)p)[i]) : ((const float*)p)[i];
}
// Flagged 8-wide input load (i multiple of 8).
DEVI void ld8(const void* p, size_t i, int bf, float r[8]) {
    if (bf) {
        const ushort8v u = *(const ushort8v*)((const unsigned short*)p + i);
#pragma unroll
        for (int k = 0; k < 8; k++) r[k] = bf2f(u[k]);
    } else {
        const float4 a = *(const float4*)((const float*)p + i);
        const float4 b = *(const float4*)((const float*)p + i + 4);
        r[0] = a.x; r[1] = a.y; r[2] = a.z; r[3] = a.w;
        r[4] = b.x; r[5] = b.y; r[6] = b.z; r[7] = b.w;
    }
}

DEVI void gload16(const void* g, void* l) {
    __builtin_amdgcn_global_load_lds(
        (const __attribute__((address_space(1))) void*)g,
        (__attribute__((address_space(3))) void*)l, 16, 0, 0);
}

// ---------------------------------------------------------------------------
// K0: dtype detect (unchanged, known-good).
// ---------------------------------------------------------------------------
__global__ __launch_bounds__(64) void detect_dtype_kernel(const void* __restrict__ xyz1,
                                                          int* __restrict__ flag)
{
    const unsigned short* u = (const unsigned short*)xyz1;
    const int lane = threadIdx.x;
    const float av = fabsf(bf2f(u[2 * lane]));
    const bool in_range = (av >= 1e-4f && av <= 100.0f);
    const unsigned long long m = __ballot(in_range);
    if (lane == 0) flag[0] = (__popcll(m) >= 32) ? 1 : 0;
}

// ---------------------------------------------------------------------------
// K0b: weights -> bf16 in workspace (copy if already bf16, else round).
// ---------------------------------------------------------------------------
__global__ __launch_bounds__(256) void wprep_kernel(
    const void* __restrict__ w0, const void* __restrict__ w1,
    unsigned short* __restrict__ w0b, unsigned short* __restrict__ w1b,
    const int* __restrict__ flag)
{
    const int bf = flag[0];
    const int n0 = H0 * CIN;        // 98304
    const int n1 = H1 * H0;         // 32768
    for (int i = blockIdx.x * blockDim.x + threadIdx.x; i < n0 + n1; i += gridDim.x * blockDim.x) {
        if (i < n0) {
            w0b[i] = bf ? ((const unsigned short*)w0)[i] : f2bf(((const float*)w0)[i]);
        } else {
            const int j = i - n0;
            w1b[j] = bf ? ((const unsigned short*)w1)[j] : f2bf(((const float*)w1)[j]);
        }
    }
}

// ---------------------------------------------------------------------------
// K1: 3-NN search (unchanged, known-good).
// ---------------------------------------------------------------------------
__global__ __launch_bounds__(256) void knn3_kernel(
    const void* __restrict__ xyz1, const void* __restrict__ xyz2,
    int* __restrict__ nn_idx, float* __restrict__ nn_w,
    const int* __restrict__ flag)
{
    const int bf = flag[0];
    const int tid = threadIdx.x;
    const int gid = blockIdx.x * 256 + tid;        // b*N + n
    const int b = gid >> 13;                       // /8192

    const float x1 = ldin(xyz1, (size_t)gid * 3 + 0, bf);
    const float y1 = ldin(xyz1, (size_t)gid * 3 + 1, bf);
    const float z1 = ldin(xyz1, (size_t)gid * 3 + 2, bf);
    const float sq1 = __fadd_rn(__fadd_rn(__fmul_rn(x1, x1), __fmul_rn(y1, y1)), __fmul_rn(z1, z1));

    float b0 = 3.4e38f, b1 = 3.4e38f, b2 = 3.4e38f;
    int   i0 = 0, i1 = 0, i2 = 0;

    __shared__ float sx[256], sy[256], sz[256], sq[256];

    for (int j0 = 0; j0 < M; j0 += 256) {
        const int j = j0 + tid;
        const float x2 = ldin(xyz2, (size_t)(b * M + j) * 3 + 0, bf);
        const float y2 = ldin(xyz2, (size_t)(b * M + j) * 3 + 1, bf);
        const float z2 = ldin(xyz2, (size_t)(b * M + j) * 3 + 2, bf);
        sx[tid] = x2; sy[tid] = y2; sz[tid] = z2;
        sq[tid] = __fadd_rn(__fadd_rn(__fmul_rn(x2, x2), __fmul_rn(y2, y2)), __fmul_rn(z2, z2));
        __syncthreads();
        for (int jj = 0; jj < 256; jj++) {
            const float inner = __fadd_rn(__fadd_rn(__fmul_rn(x1, sx[jj]), __fmul_rn(y1, sy[jj])),
                                          __fmul_rn(z1, sz[jj]));
            const float d = __fadd_rn(__fsub_rn(sq1, __fmul_rn(2.0f, inner)), sq[jj]);
            const int j2 = j0 + jj;
            if (d < b2) {
                if (d < b0)      { b2 = b1; i2 = i1; b1 = b0; i1 = i0; b0 = d; i0 = j2; }
                else if (d < b1) { b2 = b1; i2 = i1; b1 = d;  i1 = j2; }
                else             { b2 = d;  i2 = j2; }
            }
        }
        __syncthreads();
    }

    const float v0 = 1.0f / (b0 + 1e-8f);
    const float v1 = 1.0f / (b1 + 1e-8f);
    const float v2 = 1.0f / (b2 + 1e-8f);
    const float s = v0 + v1 + v2;
    nn_idx[gid * 3 + 0] = i0; nn_idx[gid * 3 + 1] = i1; nn_idx[gid * 3 + 2] = i2;
    nn_w[gid * 3 + 0] = v0 / s; nn_w[gid * 3 + 1] = v1 / s; nn_w[gid * 3 + 2] = v2 / s;
}

// ---------------------------------------------------------------------------
// K2: interpolate + concat -> feat (BN, 384) bf16.  8 channels per thread,
// fully vectorized loads/stores.
// ---------------------------------------------------------------------------
__global__ __launch_bounds__(256) void interp_concat_kernel(
    const void* __restrict__ p1, const void* __restrict__ p2,
    const int* __restrict__ nn_idx, const float* __restrict__ nn_w,
    unsigned short* __restrict__ feat, const int* __restrict__ flag)
{
    const int bf = flag[0];
    const int total = BN * (CIN / 8);              // 3145728
    for (int idx = blockIdx.x * blockDim.x + threadIdx.x; idx < total; idx += gridDim.x * blockDim.x) {
        const int c8 = idx % 48;
        const int p  = idx / 48;
        const int c  = c8 * 8;
        float r[8];
        if (c < C1) {
            ld8(p1, (size_t)p * C1 + c, bf, r);
        } else {
            const int b  = p >> 13;
            const int c2 = c - C1;
            const int*   id = nn_idx + p * 3;
            const float* wv = nn_w  + p * 3;
            float t0[8], t1[8], t2[8];
            ld8(p2, (size_t)(b * M + id[0]) * C2 + c2, bf, t0);
            ld8(p2, (size_t)(b * M + id[1]) * C2 + c2, bf, t1);
            ld8(p2, (size_t)(b * M + id[2]) * C2 + c2, bf, t2);
            const float w0v = wv[0], w1v = wv[1], w2v = wv[2];
#pragma unroll
            for (int k = 0; k < 8; k++) r[k] = w0v * t0[k] + w1v * t1[k] + w2v * t2[k];
        }
        ushort8v o;
#pragma unroll
        for (int k = 0; k < 8; k++) o[k] = f2bf(r[k]);
        *(ushort8v*)(feat + (size_t)idx * 8) = o;
    }
}

// ---------------------------------------------------------------------------
// K3/K6: bf16 MFMA GEMM (NT): C(rows,COUT) = A(rows,K) * W(COUT,K)^T.
// m97 structure: 128x128 block tile, 4 waves (2x2), BK=64, 16x16x32 MFMA,
// global_load_lds(16B) staging, 16B-slot XOR swizzle (write via pre-swizzled
// global source, read via swizzled ds_read_b128).  Output bf16.
// ---------------------------------------------------------------------------
template<int K, int COUT>
__global__ __launch_bounds__(256) void gemm_mfma_kernel(
    const unsigned short* __restrict__ A,
    const unsigned short* __restrict__ W,
    unsigned short* __restrict__ Cmat)
{
    __shared__ __align__(16) char lds[32768];      // As 16KB | Bs 16KB

    const int tid = threadIdx.x;
    const int l   = tid & 63;
    const int w   = tid >> 6;
    const int rowBase = blockIdx.x * 128;
    const int colBase = blockIdx.y * 128;

    // staging geometry: wave w owns chunks w*4..w*4+3, each 1KB = 8 rows.
    const int srow  = l >> 3;       // row within chunk
    const int sslot = l & 7;        // 16B slot within 128B row

    f32x4 acc[4][4];
#pragma unroll
    for (int i = 0; i < 4; i++)
#pragma unroll
        for (int j = 0; j < 4; j++) acc[i][j] = (f32x4)0.0f;

    // compute geometry
    const int wr  = (tid >> 7) & 1;
    const int wc  = (tid >> 6) & 1;
    const int rl  = l & 15;
    const int kq  = l >> 4;          // 0..3
    const int swz = (l & 7) << 4;    // row&7 == l&7 for all frag rows
    int aoff[4], boff[4];
#pragma unroll
    for (int i = 0; i < 4; i++) {
        aoff[i] = (wr * 64 + i * 16 + rl) * 128;
        boff[i] = 16384 + (wc * 64 + i * 16 + rl) * 128;
    }

    constexpr int NT = K / 64;

#pragma unroll 1
    for (int t = 0; t < NT; ++t) {
        {   // stage tile t (A and B), pre-swizzled global source
            const int k0 = t * 64;
#pragma unroll
            for (int i = 0; i < 4; ++i) {
                const int ch = w * 4 + i;
                const int r  = ch * 8 + srow;                 // 0..127
                const int ke = (sslot ^ (r & 7)) << 3;        // element offset in row
                gload16(A + ((size_t)(rowBase + r) * K + k0 + ke), lds + ch * 1024);
                gload16(W + ((size_t)(colBase + r) * K + k0 + ke), lds + 16384 + ch * 1024);
            }
        }
        __syncthreads();
#pragma unroll
        for (int ks = 0; ks < 2; ++ks) {
            const int kb = (ks * 64 + kq * 16) ^ swz;
            bf16x8 af[4], bfr[4];
#pragma unroll
            for (int i = 0; i < 4; i++) af[i]  = *(const bf16x8*)(lds + aoff[i] + kb);
#pragma unroll
            for (int j = 0; j < 4; j++) bfr[j] = *(const bf16x8*)(lds + boff[j] + kb);
#pragma unroll
            for (int i = 0; i < 4; i++)
#pragma unroll
                for (int j = 0; j < 4; j++)
                    acc[i][j] = __builtin_amdgcn_mfma_f32_16x16x32_bf16(af[i], bfr[j], acc[i][j], 0, 0, 0);
        }
        __syncthreads();
    }

    // C/D layout: col = lane&15, row = (lane>>4)*4 + reg   [m89 verified]
    const int crow = rowBase + wr * 64 + kq * 4;
    const int ccol = colBase + wc * 64 + rl;
#pragma unroll
    for (int i = 0; i < 4; i++)
#pragma unroll
        for (int j = 0; j < 4; j++)
#pragma unroll
            for (int r = 0; r < 4; r++)
                Cmat[(size_t)(crow + i * 16 + r) * COUT + ccol + j * 16] = f2bf(acc[i][j][r]);
}

// ---------------------------------------------------------------------------
// K4/K7: GroupNorm stats over bf16 h.  One block per (batch, group).
// ---------------------------------------------------------------------------
__global__ __launch_bounds__(256) void gn_stats_kernel(
    const unsigned short* __restrict__ h, float2* __restrict__ st, int C, int cpg)
{
    const int groups = C / cpg;
    const int b = blockIdx.x / groups;
    const int g = blockIdx.x % groups;

    float s = 0.f, ss = 0.f;
    for (int n = threadIdx.x; n < N; n += 256) {
        const unsigned short* row = h + (size_t)(b * N + n) * C + g * cpg;
        for (int c = 0; c < cpg; c += 4) {
            const ushort4 v = *(const ushort4*)(row + c);
            const float f0 = bf2f(v.x), f1 = bf2f(v.y), f2 = bf2f(v.z), f3 = bf2f(v.w);
            s  += f0 + f1 + f2 + f3;
            ss += f0 * f0 + f1 * f1 + f2 * f2 + f3 * f3;
        }
    }
    __shared__ float rs[256], rss[256];
    rs[threadIdx.x] = s; rss[threadIdx.x] = ss;
    __syncthreads();
    for (int off = 128; off > 0; off >>= 1) {
        if (threadIdx.x < off) {
            rs[threadIdx.x]  += rs[threadIdx.x + off];
            rss[threadIdx.x] += rss[threadIdx.x + off];
        }
        __syncthreads();
    }
    if (threadIdx.x == 0) {
        const float cnt = (float)N * (float)cpg;
        const float mu  = rs[0] / cnt;
        const float var = rss[0] / cnt - mu * mu;
        st[blockIdx.x] = make_float2(mu, rsqrtf(var + 1e-5f));
    }
}

// ---------------------------------------------------------------------------
// K5/K8: normalize + affine + ReLU on bf16 h.  final_out=0 -> bf16 ws buffer;
// final_out=1 -> d_out, dtype per flag.
// ---------------------------------------------------------------------------
__global__ __launch_bounds__(256) void gn_norm_relu_kernel(
    const unsigned short* __restrict__ h, const float2* __restrict__ st,
    const void* __restrict__ gw, const void* __restrict__ gb,
    void* __restrict__ out, int C, int cpg, int total4,
    const int* __restrict__ flag, int final_out)
{
    const int bf = flag[0];
    const int C4 = C >> 2;
    for (int i4 = blockIdx.x * blockDim.x + threadIdx.x; i4 < total4; i4 += gridDim.x * blockDim.x) {
        const int c = (i4 % C4) * 4;
        const int p = i4 / C4;
        const int b = p >> 13;
        const float2 ms = st[b * (C / cpg) + c / cpg];  // 4 consecutive c share a group
        const ushort4 hv = *(const ushort4*)(h + (size_t)i4 * 4);
        float r[4] = { bf2f(hv.x), bf2f(hv.y), bf2f(hv.z), bf2f(hv.w) };
#pragma unroll
        for (int k = 0; k < 4; k++) {
            const float gwv = ldin(gw, c + k, bf);
            const float gbv = ldin(gb, c + k, bf);
            r[k] = fmaxf((r[k] - ms.x) * ms.y * gwv + gbv, 0.f);
        }
        if (!final_out || bf) {
            ushort4 o;
            o.x = f2bf(r[0]); o.y = f2bf(r[1]); o.z = f2bf(r[2]); o.w = f2bf(r[3]);
            *(ushort4*)((unsigned short*)out + (size_t)i4 * 4) = o;
        } else {
            float4 o; o.x = r[0]; o.y = r[1]; o.z = r[2]; o.w = r[3];
            *(float4*)((float*)out + (size_t)i4 * 4) = o;
        }
    }
}

// ---------------------------------------------------------------------------
extern "C" void kernel_launch(void* const* d_in, const int* in_sizes, int n_in,
                              void* d_out, int out_size, void* d_ws, size_t ws_size,
                              hipStream_t stream)
{
    const void* xyz1    = d_in[0];
    const void* xyz2    = d_in[1];
    const void* points1 = d_in[2];
    const void* points2 = d_in[3];
    const void* w0      = d_in[4];
    const void* w1      = d_in[5];
    const void* gn0w    = d_in[6];
    const void* gn0b    = d_in[7];
    const void* gn1w    = d_in[8];
    const void* gn1b    = d_in[9];

    char* ws = (char*)d_ws;
    // layout (bytes):
    //      0  nn_idx   (786432)
    // 786432  nn_w     (786432)
    // 1572864 feat     bf16 BN*384*2 = 50331648   [h0n aliases this after GEMM1]
    // 51904512 h0      bf16 BN*256*2 = 33554432   [h1 aliases this after norm0]
    // 85458944 w0b     196608
    // 85655552 w1b     65536
    // 85721088 st0     2048
    // 85723136 st1     2048
    // 85725184 flag    4
    int*            nn_idx = (int*)ws;
    float*          nn_w   = (float*)(ws + 786432);
    unsigned short* feat   = (unsigned short*)(ws + 1572864);
    unsigned short* h0     = (unsigned short*)(ws + 51904512);
    unsigned short* h0n    = feat;     // feat dead after GEMM1
    unsigned short* h1     = h0;       // h0 dead after norm0
    unsigned short* w0b    = (unsigned short*)(ws + 85458944);
    unsigned short* w1b    = (unsigned short*)(ws + 85655552);
    float2*         st0    = (float2*)(ws + 85721088);
    float2*         st1    = (float2*)(ws + 85723136);
    int*            flag   = (int*)(ws + 85725184);

    detect_dtype_kernel<<<1, 64, 0, stream>>>(xyz1, flag);

    wprep_kernel<<<128, 256, 0, stream>>>(w0, w1, w0b, w1b, flag);

    knn3_kernel<<<BN / 256, 256, 0, stream>>>(xyz1, xyz2, nn_idx, nn_w, flag);

    interp_concat_kernel<<<2048, 256, 0, stream>>>(points1, points2, nn_idx, nn_w, feat, flag);

    {
        dim3 g(BN / 128, H0 / 128);   // (512, 2)
        gemm_mfma_kernel<CIN, H0><<<g, 256, 0, stream>>>(feat, w0b, h0);
    }

    gn_stats_kernel<<<B * 32, 256, 0, stream>>>(h0, st0, H0, H0 / 32);
    gn_norm_relu_kernel<<<2048, 256, 0, stream>>>(h0, st0, gn0w, gn0b, (void*)h0n,
                                                  H0, H0 / 32, BN * H0 / 4, flag, 0);

    {
        dim3 g(BN / 128, H1 / 128);   // (512, 1)
        gemm_mfma_kernel<H0, H1><<<g, 256, 0, stream>>>(h0n, w1b, h1);
    }

    gn_stats_kernel<<<B * 32, 256, 0, stream>>>(h1, st1, H1, H1 / 32);
    gn_norm_relu_kernel<<<1024, 256, 0, stream>>>(h1, st1, gn1w, gn1b, d_out,
                                                  H1, H1 / 32, BN * H1 / 4, flag, 1);
}

// Round 2
// 345.951 us; speedup vs baseline: 2.4756x; 1.4221x over previous
//
#include <hip/hip_runtime.h>

// ---------------------------------------------------------------------------
// FeaturePropagationLayer (PointNet++ FP): 3-NN interp -> concat -> MLP(384->256)
// -> GN(32)+ReLU -> MLP(256->128) -> GN(32)+ReLU.  Output (B,N,128).
//
// Round 3: knn rewrite.  xyz2 pre-packed to float4(x,y,z,sq) in ws; knn splits
// M 8-way across blockIdx.y (2048 blocks -> 8 waves/SIMD) with wave-uniform
// candidate loads (readfirstlane'd batch index -> scalar/L1 broadcast path,
// no LDS).  Tiny merge kernel combines 8x top-3 with (d,idx) tie-break.
// GroupNorm stats split over N (512 blocks, fully-coalesced full-row reads)
// + 1-block finalize.  GEMMs/interp unchanged from round 2 (bf16 MFMA).
// ---------------------------------------------------------------------------

#define DEVI __device__ __forceinline__

static constexpr int B  = 8;
static constexpr int N  = 8192;
static constexpr int M  = 2048;
static constexpr int C1 = 128;
static constexpr int C2 = 256;
static constexpr int CIN = C1 + C2;   // 384
static constexpr int H0 = 256;
static constexpr int H1 = 128;
static constexpr int BN = B * N;      // 65536
static constexpr int NSEG = 8;        // knn M-split
static constexpr int SEGL = M / NSEG; // 256
static constexpr int SL = 64;         // gn stats N-split

typedef __bf16 bf16x8 __attribute__((ext_vector_type(8)));
typedef float  f32x4  __attribute__((ext_vector_type(4)));
typedef unsigned short ushort8v __attribute__((ext_vector_type(8)));

DEVI float bf2f(unsigned short u) {
    union { unsigned int i; float f; } v; v.i = ((unsigned int)u) << 16; return v.f;
}
DEVI unsigned short f2bf(float f) {
    union { float f; unsigned int i; } v; v.f = f;
    unsigned int x = v.i;
    return (unsigned short)((x + 0x7fffu + ((x >> 16) & 1u)) >> 16);
}
DEVI float ldin(const void* p, size_t i, int bf) {
    return bf ? bf2f(((const unsigned short*)p)[i]) : ((const float*)p)[i];
}
DEVI void ld8(const void* p, size_t i, int bf, float r[8]) {
    if (bf) {
        const ushort8v u = *(const ushort8v*)((const unsigned short*)p + i);
#pragma unroll
        for (int k = 0; k < 8; k++) r[k] = bf2f(u[k]);
    } else {
        const float4 a = *(const float4*)((const float*)p + i);
        const float4 b = *(const float4*)((const float*)p + i + 4);
        r[0] = a.x; r[1] = a.y; r[2] = a.z; r[3] = a.w;
        r[4] = b.x; r[5] = b.y; r[6] = b.z; r[7] = b.w;
    }
}

DEVI void gload16(const void* g, void* l) {
    __builtin_amdgcn_global_load_lds(
        (const __attribute__((address_space(1))) void*)g,
        (__attribute__((address_space(3))) void*)l, 16, 0, 0);
}

// ---------------------------------------------------------------------------
// K0: dtype detect (unchanged, known-good).
// ---------------------------------------------------------------------------
__global__ __launch_bounds__(64) void detect_dtype_kernel(const void* __restrict__ xyz1,
                                                          int* __restrict__ flag)
{
    const unsigned short* u = (const unsigned short*)xyz1;
    const int lane = threadIdx.x;
    const float av = fabsf(bf2f(u[2 * lane]));
    const bool in_range = (av >= 1e-4f && av <= 100.0f);
    const unsigned long long m = __ballot(in_range);
    if (lane == 0) flag[0] = (__popcll(m) >= 32) ? 1 : 0;
}

// ---------------------------------------------------------------------------
// K0b: prep — weights -> bf16, xyz2 -> packed float4(x,y,z,|p|^2).
// ---------------------------------------------------------------------------
__global__ __launch_bounds__(256) void prep_kernel(
    const void* __restrict__ w0, const void* __restrict__ w1,
    const void* __restrict__ xyz2,
    unsigned short* __restrict__ w0b, unsigned short* __restrict__ w1b,
    float4* __restrict__ c4, const int* __restrict__ flag)
{
    const int bf = flag[0];
    const int n0 = H0 * CIN;        // 98304
    const int n1 = H1 * H0;         // 32768
    const int n2 = B * M;           // 16384
    const int total = n0 + n1 + n2;
    for (int i = blockIdx.x * blockDim.x + threadIdx.x; i < total; i += gridDim.x * blockDim.x) {
        if (i < n0) {
            w0b[i] = bf ? ((const unsigned short*)w0)[i] : f2bf(((const float*)w0)[i]);
        } else if (i < n0 + n1) {
            const int j = i - n0;
            w1b[j] = bf ? ((const unsigned short*)w1)[j] : f2bf(((const float*)w1)[j]);
        } else {
            const int j = i - n0 - n1;
            const float x = ldin(xyz2, (size_t)j * 3 + 0, bf);
            const float y = ldin(xyz2, (size_t)j * 3 + 1, bf);
            const float z = ldin(xyz2, (size_t)j * 3 + 2, bf);
            const float sq = __fadd_rn(__fadd_rn(__fmul_rn(x, x), __fmul_rn(y, y)), __fmul_rn(z, z));
            c4[j] = make_float4(x, y, z, sq);
        }
    }
}

// ---------------------------------------------------------------------------
// K1a: 3-NN search, M split 8-way.  blockIdx.y = segment; candidates read as
// wave-uniform float4 loads (batch index readfirstlane'd -> scalar path).
// Per-segment top-3 (strict < keeps lowest index) written to cd/ci.
// ---------------------------------------------------------------------------
__global__ __launch_bounds__(256) void knn3_split_kernel(
    const void* __restrict__ xyz1, const float4* __restrict__ c4,
    float* __restrict__ cd, int* __restrict__ ci, const int* __restrict__ flag)
{
    const int bf = flag[0];
    const int tid = threadIdx.x;
    const int gid = blockIdx.x * 256 + tid;        // b*N + n
    const int s = blockIdx.y;                      // 0..NSEG-1
    const int b = __builtin_amdgcn_readfirstlane(gid >> 13);

    const float x1 = ldin(xyz1, (size_t)gid * 3 + 0, bf);
    const float y1 = ldin(xyz1, (size_t)gid * 3 + 1, bf);
    const float z1 = ldin(xyz1, (size_t)gid * 3 + 2, bf);
    const float sq1 = __fadd_rn(__fadd_rn(__fmul_rn(x1, x1), __fmul_rn(y1, y1)), __fmul_rn(z1, z1));

    const float4* __restrict__ cand = c4 + b * M + s * SEGL;
    const int jbase = s * SEGL;

    float b0 = 3.4e38f, b1 = 3.4e38f, b2 = 3.4e38f;
    int   i0 = 0, i1 = 0, i2 = 0;

#pragma unroll 4
    for (int j = 0; j < SEGL; ++j) {
        const float4 p = cand[j];
        const float inner = __fadd_rn(__fadd_rn(__fmul_rn(x1, p.x), __fmul_rn(y1, p.y)),
                                      __fmul_rn(z1, p.z));
        const float d = __fadd_rn(__fsub_rn(sq1, __fmul_rn(2.0f, inner)), p.w);
        const int j2 = jbase + j;
        if (d < b2) {
            if (d < b0)      { b2 = b1; i2 = i1; b1 = b0; i1 = i0; b0 = d; i0 = j2; }
            else if (d < b1) { b2 = b1; i2 = i1; b1 = d;  i1 = j2; }
            else             { b2 = d;  i2 = j2; }
        }
    }

    const size_t base = (size_t)gid * (3 * NSEG) + s * 3;
    cd[base + 0] = b0; cd[base + 1] = b1; cd[base + 2] = b2;
    ci[base + 0] = i0; ci[base + 1] = i1; ci[base + 2] = i2;
}

// ---------------------------------------------------------------------------
// K1b: merge 8x top-3 -> global top-3 with (d, idx) tie-break; weights.
// ---------------------------------------------------------------------------
__global__ __launch_bounds__(256) void knn3_merge_kernel(
    const float* __restrict__ cd, const int* __restrict__ ci,
    int* __restrict__ nn_idx, float* __restrict__ nn_w)
{
    const int gid = blockIdx.x * 256 + threadIdx.x;
    const float* d24 = cd + (size_t)gid * (3 * NSEG);
    const int*   i24 = ci + (size_t)gid * (3 * NSEG);

    float bd0 = 3.4e38f, bd1 = 3.4e38f, bd2 = 3.4e38f;
    int   bi0 = 0x7fffffff, bi1 = 0x7fffffff, bi2 = 0x7fffffff;

#pragma unroll
    for (int k = 0; k < 3 * NSEG; ++k) {
        const float d  = d24[k];
        const int   ix = i24[k];
        const bool lt2 = (d < bd2) || (d == bd2 && ix < bi2);
        if (lt2) {
            const bool lt0 = (d < bd0) || (d == bd0 && ix < bi0);
            const bool lt1 = (d < bd1) || (d == bd1 && ix < bi1);
            if (lt0)      { bd2 = bd1; bi2 = bi1; bd1 = bd0; bi1 = bi0; bd0 = d; bi0 = ix; }
            else if (lt1) { bd2 = bd1; bi2 = bi1; bd1 = d; bi1 = ix; }
            else          { bd2 = d; bi2 = ix; }
        }
    }

    const float v0 = 1.0f / (bd0 + 1e-8f);
    const float v1 = 1.0f / (bd1 + 1e-8f);
    const float v2 = 1.0f / (bd2 + 1e-8f);
    const float s = v0 + v1 + v2;
    nn_idx[gid * 3 + 0] = bi0; nn_idx[gid * 3 + 1] = bi1; nn_idx[gid * 3 + 2] = bi2;
    nn_w[gid * 3 + 0] = v0 / s; nn_w[gid * 3 + 1] = v1 / s; nn_w[gid * 3 + 2] = v2 / s;
}

// ---------------------------------------------------------------------------
// K2: interpolate + concat -> feat (BN, 384) bf16 (unchanged).
// ---------------------------------------------------------------------------
__global__ __launch_bounds__(256) void interp_concat_kernel(
    const void* __restrict__ p1, const void* __restrict__ p2,
    const int* __restrict__ nn_idx, const float* __restrict__ nn_w,
    unsigned short* __restrict__ feat, const int* __restrict__ flag)
{
    const int bf = flag[0];
    const int total = BN * (CIN / 8);              // 3145728
    for (int idx = blockIdx.x * blockDim.x + threadIdx.x; idx < total; idx += gridDim.x * blockDim.x) {
        const int c8 = idx % 48;
        const int p  = idx / 48;
        const int c  = c8 * 8;
        float r[8];
        if (c < C1) {
            ld8(p1, (size_t)p * C1 + c, bf, r);
        } else {
            const int b  = p >> 13;
            const int c2 = c - C1;
            const int*   id = nn_idx + p * 3;
            const float* wv = nn_w  + p * 3;
            float t0[8], t1[8], t2[8];
            ld8(p2, (size_t)(b * M + id[0]) * C2 + c2, bf, t0);
            ld8(p2, (size_t)(b * M + id[1]) * C2 + c2, bf, t1);
            ld8(p2, (size_t)(b * M + id[2]) * C2 + c2, bf, t2);
            const float w0v = wv[0], w1v = wv[1], w2v = wv[2];
#pragma unroll
            for (int k = 0; k < 8; k++) r[k] = w0v * t0[k] + w1v * t1[k] + w2v * t2[k];
        }
        ushort8v o;
#pragma unroll
        for (int k = 0; k < 8; k++) o[k] = f2bf(r[k]);
        *(ushort8v*)(feat + (size_t)idx * 8) = o;
    }
}

// ---------------------------------------------------------------------------
// K3/K6: bf16 MFMA GEMM (NT), m97 structure (unchanged, verified).
// ---------------------------------------------------------------------------
template<int K, int COUT>
__global__ __launch_bounds__(256) void gemm_mfma_kernel(
    const unsigned short* __restrict__ A,
    const unsigned short* __restrict__ W,
    unsigned short* __restrict__ Cmat)
{
    __shared__ __align__(16) char lds[32768];      // As 16KB | Bs 16KB

    const int tid = threadIdx.x;
    const int l   = tid & 63;
    const int w   = tid >> 6;
    const int rowBase = blockIdx.x * 128;
    const int colBase = blockIdx.y * 128;

    const int srow  = l >> 3;
    const int sslot = l & 7;

    f32x4 acc[4][4];
#pragma unroll
    for (int i = 0; i < 4; i++)
#pragma unroll
        for (int j = 0; j < 4; j++) acc[i][j] = (f32x4)0.0f;

    const int wr  = (tid >> 7) & 1;
    const int wc  = (tid >> 6) & 1;
    const int rl  = l & 15;
    const int kq  = l >> 4;
    const int swz = (l & 7) << 4;
    int aoff[4], boff[4];
#pragma unroll
    for (int i = 0; i < 4; i++) {
        aoff[i] = (wr * 64 + i * 16 + rl) * 128;
        boff[i] = 16384 + (wc * 64 + i * 16 + rl) * 128;
    }

    constexpr int NT = K / 64;

#pragma unroll 1
    for (int t = 0; t < NT; ++t) {
        {
            const int k0 = t * 64;
#pragma unroll
            for (int i = 0; i < 4; ++i) {
                const int ch = w * 4 + i;
                const int r  = ch * 8 + srow;
                const int ke = (sslot ^ (r & 7)) << 3;
                gload16(A + ((size_t)(rowBase + r) * K + k0 + ke), lds + ch * 1024);
                gload16(W + ((size_t)(colBase + r) * K + k0 + ke), lds + 16384 + ch * 1024);
            }
        }
        __syncthreads();
#pragma unroll
        for (int ks = 0; ks < 2; ++ks) {
            const int kb = (ks * 64 + kq * 16) ^ swz;
            bf16x8 af[4], bfr[4];
#pragma unroll
            for (int i = 0; i < 4; i++) af[i]  = *(const bf16x8*)(lds + aoff[i] + kb);
#pragma unroll
            for (int j = 0; j < 4; j++) bfr[j] = *(const bf16x8*)(lds + boff[j] + kb);
#pragma unroll
            for (int i = 0; i < 4; i++)
#pragma unroll
                for (int j = 0; j < 4; j++)
                    acc[i][j] = __builtin_amdgcn_mfma_f32_16x16x32_bf16(af[i], bfr[j], acc[i][j], 0, 0, 0);
        }
        __syncthreads();
    }

    const int crow = rowBase + wr * 64 + kq * 4;
    const int ccol = colBase + wc * 64 + rl;
#pragma unroll
    for (int i = 0; i < 4; i++)
#pragma unroll
        for (int j = 0; j < 4; j++)
#pragma unroll
            for (int r = 0; r < 4; r++)
                Cmat[(size_t)(crow + i * 16 + r) * COUT + ccol + j * 16] = f2bf(acc[i][j][r]);
}

// ---------------------------------------------------------------------------
// K4a: GroupNorm partial stats, N split SL-way.  Block = (b, sl); lane g=t&31
// owns group g's contiguous chunk -> full-row coalesced reads.  32 groups,
// cpg = C/32 (8 for H0, 4 for H1).
// ---------------------------------------------------------------------------
__global__ __launch_bounds__(256) void gn_stats_part_kernel(
    const unsigned short* __restrict__ h, float2* __restrict__ part, int C)
{
    const int cpg = C >> 5;                 // 8 or 4
    const int b  = blockIdx.x / SL;
    const int sl = blockIdx.x % SL;
    const int g  = threadIdx.x & 31;
    const int rs = threadIdx.x >> 5;        // row slot 0..7
    const int rows = N / SL;                // 128

    float s = 0.f, ss = 0.f;
    for (int n = sl * rows + rs; n < (sl + 1) * rows; n += 8) {
        const unsigned short* row = h + (size_t)(b * N + n) * C + g * cpg;
        for (int c = 0; c < cpg; c += 4) {
            const ushort4 v = *(const ushort4*)(row + c);
            const float f0 = bf2f(v.x), f1 = bf2f(v.y), f2 = bf2f(v.z), f3 = bf2f(v.w);
            s  += f0 + f1 + f2 + f3;
            ss += f0 * f0 + f1 * f1 + f2 * f2 + f3 * f3;
        }
    }
    __shared__ float2 red[256];
    red[threadIdx.x] = make_float2(s, ss);
    __syncthreads();
    if (threadIdx.x < 32) {
        float2 a = red[threadIdx.x];
#pragma unroll
        for (int k = 1; k < 8; k++) {
            const float2 p = red[threadIdx.x + 32 * k];
            a.x += p.x; a.y += p.y;
        }
        part[(size_t)blockIdx.x * 32 + g] = a;
    }
}

// ---------------------------------------------------------------------------
// K4b: finalize stats: sum SL partials per (b,g) -> (mu, rstd).
// ---------------------------------------------------------------------------
__global__ __launch_bounds__(256) void gn_finalize_kernel(
    const float2* __restrict__ part, float2* __restrict__ st, int C)
{
    const int t = threadIdx.x;              // 256 == B*32
    const int b = t >> 5;
    const int g = t & 31;
    const int cpg = C >> 5;
    float s = 0.f, ss = 0.f;
    for (int k = 0; k < SL; k++) {
        const float2 p = part[(size_t)(b * SL + k) * 32 + g];
        s += p.x; ss += p.y;
    }
    const float cnt = (float)N * (float)cpg;
    const float mu  = s / cnt;
    const float var = ss / cnt - mu * mu;
    st[t] = make_float2(mu, rsqrtf(var + 1e-5f));
}

// ---------------------------------------------------------------------------
// K5/K8: normalize + affine + ReLU on bf16 h (unchanged).
// ---------------------------------------------------------------------------
__global__ __launch_bounds__(256) void gn_norm_relu_kernel(
    const unsigned short* __restrict__ h, const float2* __restrict__ st,
    const void* __restrict__ gw, const void* __restrict__ gb,
    void* __restrict__ out, int C, int cpg, int total4,
    const int* __restrict__ flag, int final_out)
{
    const int bf = flag[0];
    const int C4 = C >> 2;
    for (int i4 = blockIdx.x * blockDim.x + threadIdx.x; i4 < total4; i4 += gridDim.x * blockDim.x) {
        const int c = (i4 % C4) * 4;
        const int p = i4 / C4;
        const int b = p >> 13;
        const float2 ms = st[b * (C / cpg) + c / cpg];
        const ushort4 hv = *(const ushort4*)(h + (size_t)i4 * 4);
        float r[4] = { bf2f(hv.x), bf2f(hv.y), bf2f(hv.z), bf2f(hv.w) };
#pragma unroll
        for (int k = 0; k < 4; k++) {
            const float gwv = ldin(gw, c + k, bf);
            const float gbv = ldin(gb, c + k, bf);
            r[k] = fmaxf((r[k] - ms.x) * ms.y * gwv + gbv, 0.f);
        }
        if (!final_out || bf) {
            ushort4 o;
            o.x = f2bf(r[0]); o.y = f2bf(r[1]); o.z = f2bf(r[2]); o.w = f2bf(r[3]);
            *(ushort4*)((unsigned short*)out + (size_t)i4 * 4) = o;
        } else {
            float4 o; o.x = r[0]; o.y = r[1]; o.z = r[2]; o.w = r[3];
            *(float4*)((float*)out + (size_t)i4 * 4) = o;
        }
    }
}

// ---------------------------------------------------------------------------
extern "C" void kernel_launch(void* const* d_in, const int* in_sizes, int n_in,
                              void* d_out, int out_size, void* d_ws, size_t ws_size,
                              hipStream_t stream)
{
    const void* xyz1    = d_in[0];
    const void* xyz2    = d_in[1];
    const void* points1 = d_in[2];
    const void* points2 = d_in[3];
    const void* w0      = d_in[4];
    const void* w1      = d_in[5];
    const void* gn0w    = d_in[6];
    const void* gn0b    = d_in[7];
    const void* gn1w    = d_in[8];
    const void* gn1b    = d_in[9];

    char* ws = (char*)d_ws;
    // layout (bytes):
    //        0  nn_idx 786432
    //   786432  nn_w   786432
    //  1572864  feat   bf16 BN*384*2 = 50331648  [h0n aliases after GEMM1]
    // 51904512  h0     bf16 BN*256*2 = 33554432  [h1 aliases after norm0]
    // 85458944  w0b    196608
    // 85655552  w1b    65536
    // 85721088  st0    2048
    // 85723136  st1    2048
    // 85725184  flag   64
    // 85725248  c4     B*M*16 = 262144
    // 85987392  cd     BN*24*4 = 6291456
    // 92278848  ci     6291456
    // 98570304  part   B*SL*32*8 = 131072
    int*            nn_idx = (int*)ws;
    float*          nn_w   = (float*)(ws + 786432);
    unsigned short* feat   = (unsigned short*)(ws + 1572864);
    unsigned short* h0     = (unsigned short*)(ws + 51904512);
    unsigned short* h0n    = feat;
    unsigned short* h1     = h0;
    unsigned short* w0b    = (unsigned short*)(ws + 85458944);
    unsigned short* w1b    = (unsigned short*)(ws + 85655552);
    float2*         st0    = (float2*)(ws + 85721088);
    float2*         st1    = (float2*)(ws + 85723136);
    int*            flag   = (int*)(ws + 85725184);
    float4*         c4     = (float4*)(ws + 85725248);
    float*          cd     = (float*)(ws + 85987392);
    int*            ci     = (int*)(ws + 92278848);
    float2*         part   = (float2*)(ws + 98570304);

    detect_dtype_kernel<<<1, 64, 0, stream>>>(xyz1, flag);

    prep_kernel<<<576, 256, 0, stream>>>(w0, w1, xyz2, w0b, w1b, c4, flag);

    {
        dim3 g(BN / 256, NSEG);   // (256, 8)
        knn3_split_kernel<<<g, 256, 0, stream>>>(xyz1, c4, cd, ci, flag);
    }
    knn3_merge_kernel<<<BN / 256, 256, 0, stream>>>(cd, ci, nn_idx, nn_w);

    interp_concat_kernel<<<2048, 256, 0, stream>>>(points1, points2, nn_idx, nn_w, feat, flag);

    {
        dim3 g(BN / 128, H0 / 128);   // (512, 2)
        gemm_mfma_kernel<CIN, H0><<<g, 256, 0, stream>>>(feat, w0b, h0);
    }

    gn_stats_part_kernel<<<B * SL, 256, 0, stream>>>(h0, part, H0);
    gn_finalize_kernel<<<1, 256, 0, stream>>>(part, st0, H0);
    gn_norm_relu_kernel<<<2048, 256, 0, stream>>>(h0, st0, gn0w, gn0b, (void*)h0n,
                                                  H0, H0 / 32, BN * H0 / 4, flag, 0);

    {
        dim3 g(BN / 128, H1 / 128);   // (512, 1)
        gemm_mfma_kernel<H0, H1><<<g, 256, 0, stream>>>(h0n, w1b, h1);
    }

    gn_stats_part_kernel<<<B * SL, 256, 0, stream>>>(h1, part, H1);
    gn_finalize_kernel<<<1, 256, 0, stream>>>(part, st1, H1);
    gn_norm_relu_kernel<<<1024, 256, 0, stream>>>(h1, st1, gn1w, gn1b, d_out,
                                                  H1, H1 / 32, BN * H1 / 4, flag, 1);
}

// Round 3
// 331.684 us; speedup vs baseline: 2.5821x; 1.0430x over previous
//
#include <hip/hip_runtime.h>

// ---------------------------------------------------------------------------
// FeaturePropagationLayer (PointNet++ FP): 3-NN interp -> concat -> MLP(384->256)
// -> GN(32)+ReLU -> MLP(256->128) -> GN(32)+ReLU.  Output (B,N,128).
//
// Round 4: knn inner loop rebuilt.  Score = 0.5*|p|^2 - <q,p> (3 FMA, monotone
// in d); branchless stable top-3 insert (min/max/cndmask, ~17 VALU/pair vs 42).
// Split kernel stores only indices (segment-major, coalesced); merge kernel
// recomputes the EXACT reference d expression for the 24 survivors and does
// the (d, idx) tie-broken top-3 + weights.  Everything else unchanged.
// ---------------------------------------------------------------------------

#define DEVI __device__ __forceinline__

static constexpr int B  = 8;
static constexpr int N  = 8192;
static constexpr int M  = 2048;
static constexpr int C1 = 128;
static constexpr int C2 = 256;
static constexpr int CIN = C1 + C2;   // 384
static constexpr int H0 = 256;
static constexpr int H1 = 128;
static constexpr int BN = B * N;      // 65536
static constexpr int NSEG = 8;        // knn M-split
static constexpr int SEGL = M / NSEG; // 256
static constexpr int SL = 64;         // gn stats N-split

typedef __bf16 bf16x8 __attribute__((ext_vector_type(8)));
typedef float  f32x4  __attribute__((ext_vector_type(4)));
typedef unsigned short ushort8v __attribute__((ext_vector_type(8)));

DEVI float bf2f(unsigned short u) {
    union { unsigned int i; float f; } v; v.i = ((unsigned int)u) << 16; return v.f;
}
DEVI unsigned short f2bf(float f) {
    union { float f; unsigned int i; } v; v.f = f;
    unsigned int x = v.i;
    return (unsigned short)((x + 0x7fffu + ((x >> 16) & 1u)) >> 16);
}
DEVI float ldin(const void* p, size_t i, int bf) {
    return bf ? bf2f(((const unsigned short*)p)[i]) : ((const float*)p)[i];
}
DEVI void ld8(const void* p, size_t i, int bf, float r[8]) {
    if (bf) {
        const ushort8v u = *(const ushort8v*)((const unsigned short*)p + i);
#pragma unroll
        for (int k = 0; k < 8; k++) r[k] = bf2f(u[k]);
    } else {
        const float4 a = *(const float4*)((const float*)p + i);
        const float4 b = *(const float4*)((const float*)p + i + 4);
        r[0] = a.x; r[1] = a.y; r[2] = a.z; r[3] = a.w;
        r[4] = b.x; r[5] = b.y; r[6] = b.z; r[7] = b.w;
    }
}

DEVI void gload16(const void* g, void* l) {
    __builtin_amdgcn_global_load_lds(
        (const __attribute__((address_space(1))) void*)g,
        (__attribute__((address_space(3))) void*)l, 16, 0, 0);
}

// ---------------------------------------------------------------------------
// K0: dtype detect (unchanged, known-good).
// ---------------------------------------------------------------------------
__global__ __launch_bounds__(64) void detect_dtype_kernel(const void* __restrict__ xyz1,
                                                          int* __restrict__ flag)
{
    const unsigned short* u = (const unsigned short*)xyz1;
    const int lane = threadIdx.x;
    const float av = fabsf(bf2f(u[2 * lane]));
    const bool in_range = (av >= 1e-4f && av <= 100.0f);
    const unsigned long long m = __ballot(in_range);
    if (lane == 0) flag[0] = (__popcll(m) >= 32) ? 1 : 0;
}

// ---------------------------------------------------------------------------
// K0b: prep — weights -> bf16, xyz2 -> packed float4(x,y,z,0.5*|p|^2).
// ---------------------------------------------------------------------------
__global__ __launch_bounds__(256) void prep_kernel(
    const void* __restrict__ w0, const void* __restrict__ w1,
    const void* __restrict__ xyz2,
    unsigned short* __restrict__ w0b, unsigned short* __restrict__ w1b,
    float4* __restrict__ c4, const int* __restrict__ flag)
{
    const int bf = flag[0];
    const int n0 = H0 * CIN;        // 98304
    const int n1 = H1 * H0;         // 32768
    const int n2 = B * M;           // 16384
    const int total = n0 + n1 + n2;
    for (int i = blockIdx.x * blockDim.x + threadIdx.x; i < total; i += gridDim.x * blockDim.x) {
        if (i < n0) {
            w0b[i] = bf ? ((const unsigned short*)w0)[i] : f2bf(((const float*)w0)[i]);
        } else if (i < n0 + n1) {
            const int j = i - n0;
            w1b[j] = bf ? ((const unsigned short*)w1)[j] : f2bf(((const float*)w1)[j]);
        } else {
            const int j = i - n0 - n1;
            const float x = ldin(xyz2, (size_t)j * 3 + 0, bf);
            const float y = ldin(xyz2, (size_t)j * 3 + 1, bf);
            const float z = ldin(xyz2, (size_t)j * 3 + 2, bf);
            const float sq = __fadd_rn(__fadd_rn(__fmul_rn(x, x), __fmul_rn(y, y)), __fmul_rn(z, z));
            c4[j] = make_float4(x, y, z, 0.5f * sq);
        }
    }
}

// ---------------------------------------------------------------------------
// K1a: 3-NN search, M split 8-way.  Score s = 0.5|p|^2 - <q,p> (3 FMA; d =
// 2s + sq1 is monotone in s).  Branchless stable top-3 insert: values via
// min/max cascade, indices via cndmask on strict-< masks (tie keeps earlier
// index).  Stores only indices, segment-major (coalesced).
// ---------------------------------------------------------------------------
__global__ __launch_bounds__(256) void knn3_split_kernel(
    const void* __restrict__ xyz1, const float4* __restrict__ c4,
    int* __restrict__ ci, const int* __restrict__ flag)
{
    const int bf = flag[0];
    const int tid = threadIdx.x;
    const int gid = blockIdx.x * 256 + tid;        // b*N + n
    const int s = blockIdx.y;                      // 0..NSEG-1
    const int b = __builtin_amdgcn_readfirstlane(gid >> 13);

    const float x1 = ldin(xyz1, (size_t)gid * 3 + 0, bf);
    const float y1 = ldin(xyz1, (size_t)gid * 3 + 1, bf);
    const float z1 = ldin(xyz1, (size_t)gid * 3 + 2, bf);

    const float4* __restrict__ cand = c4 + b * M + s * SEGL;
    const int jbase = s * SEGL;

    float b0 = 3.4e38f, b1 = 3.4e38f, b2 = 3.4e38f;
    int   i0 = 0, i1 = 0, i2 = 0;

#pragma unroll 4
    for (int j = 0; j < SEGL; ++j) {
        const float4 p = cand[j];
        const float sc = __builtin_fmaf(-x1, p.x,
                          __builtin_fmaf(-y1, p.y,
                           __builtin_fmaf(-z1, p.z, p.w)));
        const int jn = jbase + j;                  // wave-uniform (SGPR)
        const bool c0 = sc < b0;
        const float t1 = fmaxf(sc, b0);
        b0 = fminf(sc, b0);
        const int  tj1 = c0 ? i0 : jn;
        i0 = c0 ? jn : i0;
        const bool c1 = t1 < b1;
        const float t2 = fmaxf(t1, b1);
        b1 = fminf(t1, b1);
        const int  tj2 = c1 ? i1 : tj1;
        i1 = c1 ? tj1 : i1;
        const bool c2 = t2 < b2;
        b2 = fminf(t2, b2);
        i2 = c2 ? tj2 : i2;
    }

    ci[(size_t)(s * 3 + 0) * BN + gid] = i0;
    ci[(size_t)(s * 3 + 1) * BN + gid] = i1;
    ci[(size_t)(s * 3 + 2) * BN + gid] = i2;
}

// ---------------------------------------------------------------------------
// K1b: merge 8x top-3.  Recomputes the EXACT reference distance expression
// for each of the 24 survivors, then (d, idx) tie-broken top-3 + weights.
// ---------------------------------------------------------------------------
__global__ __launch_bounds__(256) void knn3_merge_kernel(
    const void* __restrict__ xyz1, const float4* __restrict__ c4,
    const int* __restrict__ ci,
    int* __restrict__ nn_idx, float* __restrict__ nn_w,
    const int* __restrict__ flag)
{
    const int bf = flag[0];
    const int gid = blockIdx.x * 256 + threadIdx.x;
    const int b = gid >> 13;

    const float x1 = ldin(xyz1, (size_t)gid * 3 + 0, bf);
    const float y1 = ldin(xyz1, (size_t)gid * 3 + 1, bf);
    const float z1 = ldin(xyz1, (size_t)gid * 3 + 2, bf);
    const float sq1 = __fadd_rn(__fadd_rn(__fmul_rn(x1, x1), __fmul_rn(y1, y1)), __fmul_rn(z1, z1));

    float bd0 = 3.4e38f, bd1 = 3.4e38f, bd2 = 3.4e38f;
    int   bi0 = 0x7fffffff, bi1 = 0x7fffffff, bi2 = 0x7fffffff;

#pragma unroll
    for (int k = 0; k < 3 * NSEG; ++k) {
        const int ix = ci[(size_t)k * BN + gid];
        const float4 p = c4[b * M + ix];
        const float inner = __fadd_rn(__fadd_rn(__fmul_rn(x1, p.x), __fmul_rn(y1, p.y)),
                                      __fmul_rn(z1, p.z));
        const float pw2 = p.w + p.w;               // exact: 0.5*sq * 2
        const float d = __fadd_rn(__fsub_rn(sq1, __fmul_rn(2.0f, inner)), pw2);
        const bool lt2 = (d < bd2) || (d == bd2 && ix < bi2);
        if (lt2) {
            const bool lt0 = (d < bd0) || (d == bd0 && ix < bi0);
            const bool lt1 = (d < bd1) || (d == bd1 && ix < bi1);
            if (lt0)      { bd2 = bd1; bi2 = bi1; bd1 = bd0; bi1 = bi0; bd0 = d; bi0 = ix; }
            else if (lt1) { bd2 = bd1; bi2 = bi1; bd1 = d; bi1 = ix; }
            else          { bd2 = d; bi2 = ix; }
        }
    }

    const float v0 = 1.0f / (bd0 + 1e-8f);
    const float v1 = 1.0f / (bd1 + 1e-8f);
    const float v2 = 1.0f / (bd2 + 1e-8f);
    const float s = v0 + v1 + v2;
    nn_idx[gid * 3 + 0] = bi0; nn_idx[gid * 3 + 1] = bi1; nn_idx[gid * 3 + 2] = bi2;
    nn_w[gid * 3 + 0] = v0 / s; nn_w[gid * 3 + 1] = v1 / s; nn_w[gid * 3 + 2] = v2 / s;
}

// ---------------------------------------------------------------------------
// K2: interpolate + concat -> feat (BN, 384) bf16 (unchanged).
// ---------------------------------------------------------------------------
__global__ __launch_bounds__(256) void interp_concat_kernel(
    const void* __restrict__ p1, const void* __restrict__ p2,
    const int* __restrict__ nn_idx, const float* __restrict__ nn_w,
    unsigned short* __restrict__ feat, const int* __restrict__ flag)
{
    const int bf = flag[0];
    const int total = BN * (CIN / 8);              // 3145728
    for (int idx = blockIdx.x * blockDim.x + threadIdx.x; idx < total; idx += gridDim.x * blockDim.x) {
        const int c8 = idx % 48;
        const int p  = idx / 48;
        const int c  = c8 * 8;
        float r[8];
        if (c < C1) {
            ld8(p1, (size_t)p * C1 + c, bf, r);
        } else {
            const int b  = p >> 13;
            const int c2 = c - C1;
            const int*   id = nn_idx + p * 3;
            const float* wv = nn_w  + p * 3;
            float t0[8], t1[8], t2[8];
            ld8(p2, (size_t)(b * M + id[0]) * C2 + c2, bf, t0);
            ld8(p2, (size_t)(b * M + id[1]) * C2 + c2, bf, t1);
            ld8(p2, (size_t)(b * M + id[2]) * C2 + c2, bf, t2);
            const float w0v = wv[0], w1v = wv[1], w2v = wv[2];
#pragma unroll
            for (int k = 0; k < 8; k++) r[k] = w0v * t0[k] + w1v * t1[k] + w2v * t2[k];
        }
        ushort8v o;
#pragma unroll
        for (int k = 0; k < 8; k++) o[k] = f2bf(r[k]);
        *(ushort8v*)(feat + (size_t)idx * 8) = o;
    }
}

// ---------------------------------------------------------------------------
// K3/K6: bf16 MFMA GEMM (NT), m97 structure (unchanged, verified).
// ---------------------------------------------------------------------------
template<int K, int COUT>
__global__ __launch_bounds__(256) void gemm_mfma_kernel(
    const unsigned short* __restrict__ A,
    const unsigned short* __restrict__ W,
    unsigned short* __restrict__ Cmat)
{
    __shared__ __align__(16) char lds[32768];      // As 16KB | Bs 16KB

    const int tid = threadIdx.x;
    const int l   = tid & 63;
    const int w   = tid >> 6;
    const int rowBase = blockIdx.x * 128;
    const int colBase = blockIdx.y * 128;

    const int srow  = l >> 3;
    const int sslot = l & 7;

    f32x4 acc[4][4];
#pragma unroll
    for (int i = 0; i < 4; i++)
#pragma unroll
        for (int j = 0; j < 4; j++) acc[i][j] = (f32x4)0.0f;

    const int wr  = (tid >> 7) & 1;
    const int wc  = (tid >> 6) & 1;
    const int rl  = l & 15;
    const int kq  = l >> 4;
    const int swz = (l & 7) << 4;
    int aoff[4], boff[4];
#pragma unroll
    for (int i = 0; i < 4; i++) {
        aoff[i] = (wr * 64 + i * 16 + rl) * 128;
        boff[i] = 16384 + (wc * 64 + i * 16 + rl) * 128;
    }

    constexpr int NT = K / 64;

#pragma unroll 1
    for (int t = 0; t < NT; ++t) {
        {
            const int k0 = t * 64;
#pragma unroll
            for (int i = 0; i < 4; ++i) {
                const int ch = w * 4 + i;
                const int r  = ch * 8 + srow;
                const int ke = (sslot ^ (r & 7)) << 3;
                gload16(A + ((size_t)(rowBase + r) * K + k0 + ke), lds + ch * 1024);
                gload16(W + ((size_t)(colBase + r) * K + k0 + ke), lds + 16384 + ch * 1024);
            }
        }
        __syncthreads();
#pragma unroll
        for (int ks = 0; ks < 2; ++ks) {
            const int kb = (ks * 64 + kq * 16) ^ swz;
            bf16x8 af[4], bfr[4];
#pragma unroll
            for (int i = 0; i < 4; i++) af[i]  = *(const bf16x8*)(lds + aoff[i] + kb);
#pragma unroll
            for (int j = 0; j < 4; j++) bfr[j] = *(const bf16x8*)(lds + boff[j] + kb);
#pragma unroll
            for (int i = 0; i < 4; i++)
#pragma unroll
                for (int j = 0; j < 4; j++)
                    acc[i][j] = __builtin_amdgcn_mfma_f32_16x16x32_bf16(af[i], bfr[j], acc[i][j], 0, 0, 0);
        }
        __syncthreads();
    }

    const int crow = rowBase + wr * 64 + kq * 4;
    const int ccol = colBase + wc * 64 + rl;
#pragma unroll
    for (int i = 0; i < 4; i++)
#pragma unroll
        for (int j = 0; j < 4; j++)
#pragma unroll
            for (int r = 0; r < 4; r++)
                Cmat[(size_t)(crow + i * 16 + r) * COUT + ccol + j * 16] = f2bf(acc[i][j][r]);
}

// ---------------------------------------------------------------------------
// K4a: GroupNorm partial stats, N split SL-way (unchanged).
// ---------------------------------------------------------------------------
__global__ __launch_bounds__(256) void gn_stats_part_kernel(
    const unsigned short* __restrict__ h, float2* __restrict__ part, int C)
{
    const int cpg = C >> 5;                 // 8 or 4
    const int b  = blockIdx.x / SL;
    const int sl = blockIdx.x % SL;
    const int g  = threadIdx.x & 31;
    const int rs = threadIdx.x >> 5;        // row slot 0..7
    const int rows = N / SL;                // 128

    float s = 0.f, ss = 0.f;
    for (int n = sl * rows + rs; n < (sl + 1) * rows; n += 8) {
        const unsigned short* row = h + (size_t)(b * N + n) * C + g * cpg;
        for (int c = 0; c < cpg; c += 4) {
            const ushort4 v = *(const ushort4*)(row + c);
            const float f0 = bf2f(v.x), f1 = bf2f(v.y), f2 = bf2f(v.z), f3 = bf2f(v.w);
            s  += f0 + f1 + f2 + f3;
            ss += f0 * f0 + f1 * f1 + f2 * f2 + f3 * f3;
        }
    }
    __shared__ float2 red[256];
    red[threadIdx.x] = make_float2(s, ss);
    __syncthreads();
    if (threadIdx.x < 32) {
        float2 a = red[threadIdx.x];
#pragma unroll
        for (int k = 1; k < 8; k++) {
            const float2 p = red[threadIdx.x + 32 * k];
            a.x += p.x; a.y += p.y;
        }
        part[(size_t)blockIdx.x * 32 + g] = a;
    }
}

// ---------------------------------------------------------------------------
// K4b: finalize stats (unchanged).
// ---------------------------------------------------------------------------
__global__ __launch_bounds__(256) void gn_finalize_kernel(
    const float2* __restrict__ part, float2* __restrict__ st, int C)
{
    const int t = threadIdx.x;              // 256 == B*32
    const int b = t >> 5;
    const int g = t & 31;
    const int cpg = C >> 5;
    float s = 0.f, ss = 0.f;
    for (int k = 0; k < SL; k++) {
        const float2 p = part[(size_t)(b * SL + k) * 32 + g];
        s += p.x; ss += p.y;
    }
    const float cnt = (float)N * (float)cpg;
    const float mu  = s / cnt;
    const float var = ss / cnt - mu * mu;
    st[t] = make_float2(mu, rsqrtf(var + 1e-5f));
}

// ---------------------------------------------------------------------------
// K5/K8: normalize + affine + ReLU on bf16 h (unchanged).
// ---------------------------------------------------------------------------
__global__ __launch_bounds__(256) void gn_norm_relu_kernel(
    const unsigned short* __restrict__ h, const float2* __restrict__ st,
    const void* __restrict__ gw, const void* __restrict__ gb,
    void* __restrict__ out, int C, int cpg, int total4,
    const int* __restrict__ flag, int final_out)
{
    const int bf = flag[0];
    const int C4 = C >> 2;
    for (int i4 = blockIdx.x * blockDim.x + threadIdx.x; i4 < total4; i4 += gridDim.x * blockDim.x) {
        const int c = (i4 % C4) * 4;
        const int p = i4 / C4;
        const int b = p >> 13;
        const float2 ms = st[b * (C / cpg) + c / cpg];
        const ushort4 hv = *(const ushort4*)(h + (size_t)i4 * 4);
        float r[4] = { bf2f(hv.x), bf2f(hv.y), bf2f(hv.z), bf2f(hv.w) };
#pragma unroll
        for (int k = 0; k < 4; k++) {
            const float gwv = ldin(gw, c + k, bf);
            const float gbv = ldin(gb, c + k, bf);
            r[k] = fmaxf((r[k] - ms.x) * ms.y * gwv + gbv, 0.f);
        }
        if (!final_out || bf) {
            ushort4 o;
            o.x = f2bf(r[0]); o.y = f2bf(r[1]); o.z = f2bf(r[2]); o.w = f2bf(r[3]);
            *(ushort4*)((unsigned short*)out + (size_t)i4 * 4) = o;
        } else {
            float4 o; o.x = r[0]; o.y = r[1]; o.z = r[2]; o.w = r[3];
            *(float4*)((float*)out + (size_t)i4 * 4) = o;
        }
    }
}

// ---------------------------------------------------------------------------
extern "C" void kernel_launch(void* const* d_in, const int* in_sizes, int n_in,
                              void* d_out, int out_size, void* d_ws, size_t ws_size,
                              hipStream_t stream)
{
    const void* xyz1    = d_in[0];
    const void* xyz2    = d_in[1];
    const void* points1 = d_in[2];
    const void* points2 = d_in[3];
    const void* w0      = d_in[4];
    const void* w1      = d_in[5];
    const void* gn0w    = d_in[6];
    const void* gn0b    = d_in[7];
    const void* gn1w    = d_in[8];
    const void* gn1b    = d_in[9];

    char* ws = (char*)d_ws;
    // layout (bytes):
    //        0  nn_idx 786432
    //   786432  nn_w   786432
    //  1572864  feat   bf16 BN*384*2 = 50331648  [h0n aliases after GEMM1]
    // 51904512  h0     bf16 BN*256*2 = 33554432  [h1 aliases after norm0]
    // 85458944  w0b    196608
    // 85655552  w1b    65536
    // 85721088  st0    2048
    // 85723136  st1    2048
    // 85725184  flag   64
    // 85725248  c4     B*M*16 = 262144
    // 85987392  ci     BN*24*4 = 6291456
    // 92278848  part   B*SL*32*8 = 131072
    int*            nn_idx = (int*)ws;
    float*          nn_w   = (float*)(ws + 786432);
    unsigned short* feat   = (unsigned short*)(ws + 1572864);
    unsigned short* h0     = (unsigned short*)(ws + 51904512);
    unsigned short* h0n    = feat;
    unsigned short* h1     = h0;
    unsigned short* w0b    = (unsigned short*)(ws + 85458944);
    unsigned short* w1b    = (unsigned short*)(ws + 85655552);
    float2*         st0    = (float2*)(ws + 85721088);
    float2*         st1    = (float2*)(ws + 85723136);
    int*            flag   = (int*)(ws + 85725184);
    float4*         c4     = (float4*)(ws + 85725248);
    int*            ci     = (int*)(ws + 85987392);
    float2*         part   = (float2*)(ws + 92278848);

    detect_dtype_kernel<<<1, 64, 0, stream>>>(xyz1, flag);

    prep_kernel<<<576, 256, 0, stream>>>(w0, w1, xyz2, w0b, w1b, c4, flag);

    {
        dim3 g(BN / 256, NSEG);   // (256, 8)
        knn3_split_kernel<<<g, 256, 0, stream>>>(xyz1, c4, ci, flag);
    }
    knn3_merge_kernel<<<BN / 256, 256, 0, stream>>>(xyz1, c4, ci, nn_idx, nn_w, flag);

    interp_concat_kernel<<<2048, 256, 0, stream>>>(points1, points2, nn_idx, nn_w, feat, flag);

    {
        dim3 g(BN / 128, H0 / 128);   // (512, 2)
        gemm_mfma_kernel<CIN, H0><<<g, 256, 0, stream>>>(feat, w0b, h0);
    }

    gn_stats_part_kernel<<<B * SL, 256, 0, stream>>>(h0, part, H0);
    gn_finalize_kernel<<<1, 256, 0, stream>>>(part, st0, H0);
    gn_norm_relu_kernel<<<2048, 256, 0, stream>>>(h0, st0, gn0w, gn0b, (void*)h0n,
                                                  H0, H0 / 32, BN * H0 / 4, flag, 0);

    {
        dim3 g(BN / 128, H1 / 128);   // (512, 1)
        gemm_mfma_kernel<H0, H1><<<g, 256, 0, stream>>>(h0n, w1b, h1);
    }

    gn_stats_part_kernel<<<B * SL, 256, 0, stream>>>(h1, part, H1);
    gn_finalize_kernel<<<1, 256, 0, stream>>>(part, st1, H1);
    gn_norm_relu_kernel<<<1024, 256, 0, stream>>>(h1, st1, gn1w, gn1b, d_out,
                                                  H1, H1 / 32, BN * H1 / 4, flag, 1);
}